// Round 3
// baseline (423.828 us; speedup 1.0000x reference)
//
#include <hip/hip_runtime.h>

// SparseProjector: out[b, idx[j]] = tau[b, j] * w[j], rest zeros.
// R3: same structure as R2 (per-block 1024-pixel range, 32-row loop,
// inv+weights register-resident) but PLAIN stores instead of nontemporal.
// Theory: write-back L2 aggregates full 128B lines and drains at fill-rate
// (6.6 TB/s, per harness fill kernels); NT/streaming stores throttle it.

typedef int   iv4 __attribute__((ext_vector_type(4)));
typedef float fv4 __attribute__((ext_vector_type(4)));

__global__ void fill_inv_kernel(int* __restrict__ inv, int n4) {
    int t = blockIdx.x * blockDim.x + threadIdx.x;
    int stride = gridDim.x * blockDim.x;
    iv4 m = (iv4)(-1);
    for (int i = t; i < n4; i += stride)
        ((iv4*)inv)[i] = m;
}

__global__ void build_inv_kernel(const int* __restrict__ idx,
                                 int* __restrict__ inv, int na) {
    int j = blockIdx.x * blockDim.x + threadIdx.x;
    if (j < na) inv[idx[j]] = j;   // indices unique -> no race
}

// grid: (n4/256, ROW_GROUPS). Each thread: 4 consecutive pixels, rows_per_blk rows.
__global__ __launch_bounds__(256)
void gather_rows_kernel(const float* __restrict__ tau,
                        const float* __restrict__ w,
                        const int* __restrict__ inv,
                        float* __restrict__ out,
                        int na, int p, int n4,
                        int rows_per_blk, int batch) {
    int p4 = blockIdx.x * blockDim.x + threadIdx.x;
    if (p4 >= n4) return;

    iv4 iv = ((const iv4*)inv)[p4];          // read once, lives in VGPRs
    float w0 = (iv.x >= 0) ? w[iv.x] : 0.0f; // row-invariant weights, hoisted
    float w1 = (iv.y >= 0) ? w[iv.y] : 0.0f;
    float w2 = (iv.z >= 0) ? w[iv.z] : 0.0f;
    float w3 = (iv.w >= 0) ? w[iv.w] : 0.0f;

    int b0 = blockIdx.y * rows_per_blk;
    int bend = b0 + rows_per_blk;
    if (bend > batch) bend = batch;

    const float* taub = tau + (size_t)b0 * (size_t)na;
    fv4* dst = (fv4*)(out + (size_t)b0 * (size_t)p) + p4;
    int pq = p >> 2;

    #pragma unroll 4
    for (int b = b0; b < bend; ++b) {
        fv4 o;
        o.x = (iv.x >= 0) ? taub[iv.x] * w0 : 0.0f;
        o.y = (iv.y >= 0) ? taub[iv.y] * w1 : 0.0f;
        o.z = (iv.z >= 0) ? taub[iv.z] * w2 : 0.0f;
        o.w = (iv.w >= 0) ? taub[iv.w] * w3 : 0.0f;
        *dst = o;                 // plain write-back store (A/B vs R2's NT)
        taub += na;
        dst += pq;
    }
}

// ---------- fallback path (only if ws_size too small for inv map) ----------
__global__ void zero_out_kernel(float* __restrict__ out, long long n4) {
    long long t = (long long)blockIdx.x * blockDim.x + threadIdx.x;
    long long stride = (long long)gridDim.x * blockDim.x;
    fv4 z = (fv4)(0.0f);
    for (long long i = t; i < n4; i += stride)
        ((fv4*)out)[i] = z;
}

__global__ void scatter_kernel(const float* __restrict__ tau,
                               const float* __restrict__ w,
                               const int* __restrict__ idx,
                               float* __restrict__ out,
                               int na, int p, int batch) {
    int j = blockIdx.x * blockDim.x + threadIdx.x;
    if (j >= na) return;
    int pix = idx[j];
    float ww = w[j];
    for (int b = 0; b < batch; ++b)
        out[(size_t)b * p + pix] = tau[(size_t)b * na + j] * ww;
}

extern "C" void kernel_launch(void* const* d_in, const int* in_sizes, int n_in,
                              void* d_out, int out_size, void* d_ws, size_t ws_size,
                              hipStream_t stream) {
    const float* tau = (const float*)d_in[0];
    const float* w   = (const float*)d_in[1];
    const int*   idx = (const int*)d_in[2];
    float* out = (float*)d_out;

    int na = in_sizes[1];                        // 65536
    int batch = in_sizes[0] / na;                // 256
    int p = (int)((long long)out_size / batch);  // 1048576

    if (ws_size >= (size_t)p * sizeof(int) && (p % 1024) == 0) {
        int* inv = (int*)d_ws;
        int n4 = p / 4;
        fill_inv_kernel<<<dim3(1024), dim3(256), 0, stream>>>(inv, n4);
        build_inv_kernel<<<dim3((na + 255) / 256), dim3(256), 0, stream>>>(idx, inv, na);

        const int ROW_GROUPS = 8;
        int rows_per_blk = (batch + ROW_GROUPS - 1) / ROW_GROUPS;  // 32
        dim3 grid(n4 / 256, ROW_GROUPS);
        gather_rows_kernel<<<grid, dim3(256), 0, stream>>>(
            tau, w, inv, out, na, p, n4, rows_per_blk, batch);
    } else {
        long long n4 = ((long long)out_size) / 4;
        zero_out_kernel<<<dim3(2048), dim3(256), 0, stream>>>(out, n4);
        scatter_kernel<<<dim3((na + 255) / 256), dim3(256), 0, stream>>>(
            tau, w, idx, out, na, p, batch);
    }
}

// Round 4
// 352.770 us; speedup vs baseline: 1.2014x; 1.2014x over previous
//
#include <hip/hip_runtime.h>

// SparseProjector: out[b, idx[j]] = tau[b, j] * w[j], rest zeros.
// R4: NT stores restored (R3 proved plain stores trigger ~1 GiB of L2
// read-for-ownership traffic: 220 -> 424 us). New: 8 pixels/thread
// (two fv4 NT stores per row-iter) and ROW_GROUPS=4 (inv traffic 32->16 MB).

typedef int   iv4 __attribute__((ext_vector_type(4)));
typedef float fv4 __attribute__((ext_vector_type(4)));

__global__ void fill_inv_kernel(int* __restrict__ inv, int n4) {
    int t = blockIdx.x * blockDim.x + threadIdx.x;
    int stride = gridDim.x * blockDim.x;
    iv4 m = (iv4)(-1);
    for (int i = t; i < n4; i += stride)
        ((iv4*)inv)[i] = m;
}

__global__ void build_inv_kernel(const int* __restrict__ idx,
                                 int* __restrict__ inv, int na) {
    int j = blockIdx.x * blockDim.x + threadIdx.x;
    if (j < na) inv[idx[j]] = j;   // indices unique -> no race
}

// grid: (p/8/256, ROW_GROUPS). Each thread: 8 consecutive pixels, rows_per_blk rows.
__global__ __launch_bounds__(256)
void gather_rows_kernel(const float* __restrict__ tau,
                        const float* __restrict__ w,
                        const int* __restrict__ inv,
                        float* __restrict__ out,
                        int na, int p,
                        int rows_per_blk, int batch) {
    int t8 = blockIdx.x * blockDim.x + threadIdx.x;   // index of 8-pixel chunk

    iv4 ia = ((const iv4*)inv)[2 * t8];               // read once -> VGPRs
    iv4 ib = ((const iv4*)inv)[2 * t8 + 1];
    float w0 = (ia.x >= 0) ? w[ia.x] : 0.0f;          // row-invariant weights
    float w1 = (ia.y >= 0) ? w[ia.y] : 0.0f;
    float w2 = (ia.z >= 0) ? w[ia.z] : 0.0f;
    float w3 = (ia.w >= 0) ? w[ia.w] : 0.0f;
    float w4 = (ib.x >= 0) ? w[ib.x] : 0.0f;
    float w5 = (ib.y >= 0) ? w[ib.y] : 0.0f;
    float w6 = (ib.z >= 0) ? w[ib.z] : 0.0f;
    float w7 = (ib.w >= 0) ? w[ib.w] : 0.0f;

    int b0 = blockIdx.y * rows_per_blk;
    int bend = b0 + rows_per_blk;
    if (bend > batch) bend = batch;

    const float* taub = tau + (size_t)b0 * (size_t)na;
    fv4* dst = (fv4*)(out + (size_t)b0 * (size_t)p) + 2 * t8;
    int pq = p >> 2;

    #pragma unroll 4
    for (int b = b0; b < bend; ++b) {
        fv4 oa, ob;
        oa.x = (ia.x >= 0) ? taub[ia.x] * w0 : 0.0f;
        oa.y = (ia.y >= 0) ? taub[ia.y] * w1 : 0.0f;
        oa.z = (ia.z >= 0) ? taub[ia.z] * w2 : 0.0f;
        oa.w = (ia.w >= 0) ? taub[ia.w] * w3 : 0.0f;
        ob.x = (ib.x >= 0) ? taub[ib.x] * w4 : 0.0f;
        ob.y = (ib.y >= 0) ? taub[ib.y] * w5 : 0.0f;
        ob.z = (ib.z >= 0) ? taub[ib.z] * w6 : 0.0f;
        ob.w = (ib.w >= 0) ? taub[ib.w] * w7 : 0.0f;
        __builtin_nontemporal_store(oa, dst);
        __builtin_nontemporal_store(ob, dst + 1);
        taub += na;
        dst += pq;
    }
}

// ---------- fallback path (only if ws_size too small for inv map) ----------
__global__ void zero_out_kernel(float* __restrict__ out, long long n4) {
    long long t = (long long)blockIdx.x * blockDim.x + threadIdx.x;
    long long stride = (long long)gridDim.x * blockDim.x;
    fv4 z = (fv4)(0.0f);
    for (long long i = t; i < n4; i += stride)
        __builtin_nontemporal_store(z, (fv4*)out + i);
}

__global__ void scatter_kernel(const float* __restrict__ tau,
                               const float* __restrict__ w,
                               const int* __restrict__ idx,
                               float* __restrict__ out,
                               int na, int p, int batch) {
    int j = blockIdx.x * blockDim.x + threadIdx.x;
    if (j >= na) return;
    int pix = idx[j];
    float ww = w[j];
    for (int b = 0; b < batch; ++b)
        out[(size_t)b * p + pix] = tau[(size_t)b * na + j] * ww;
}

extern "C" void kernel_launch(void* const* d_in, const int* in_sizes, int n_in,
                              void* d_out, int out_size, void* d_ws, size_t ws_size,
                              hipStream_t stream) {
    const float* tau = (const float*)d_in[0];
    const float* w   = (const float*)d_in[1];
    const int*   idx = (const int*)d_in[2];
    float* out = (float*)d_out;

    int na = in_sizes[1];                        // 65536
    int batch = in_sizes[0] / na;                // 256
    int p = (int)((long long)out_size / batch);  // 1048576

    if (ws_size >= (size_t)p * sizeof(int) && (p % 2048) == 0) {
        int* inv = (int*)d_ws;
        int n4 = p / 4;
        fill_inv_kernel<<<dim3(1024), dim3(256), 0, stream>>>(inv, n4);
        build_inv_kernel<<<dim3((na + 255) / 256), dim3(256), 0, stream>>>(idx, inv, na);

        const int ROW_GROUPS = 4;
        int rows_per_blk = (batch + ROW_GROUPS - 1) / ROW_GROUPS;  // 64
        dim3 grid(p / 8 / 256, ROW_GROUPS);                         // 512 x 4
        gather_rows_kernel<<<grid, dim3(256), 0, stream>>>(
            tau, w, inv, out, na, p, rows_per_blk, batch);
    } else {
        long long n4 = ((long long)out_size) / 4;
        zero_out_kernel<<<dim3(2048), dim3(256), 0, stream>>>(out, n4);
        scatter_kernel<<<dim3((na + 255) / 256), dim3(256), 0, stream>>>(
            tau, w, idx, out, na, p, batch);
    }
}

// Round 5
// 203.914 us; speedup vs baseline: 2.0785x; 1.7300x over previous
//
#include <hip/hip_runtime.h>

// SparseProjector: out[b, idx[j]] = tau[b, j] * w[j], rest zeros.
// R5: R2 store pattern restored (one fv4 NT store per thread per row —
// R4 proved 2-chunk-per-thread breaks wave coalescing: 220 -> 353 us).
// New: XCD-aware 1D grid. xcd = bid & 7 picks the ROW-GROUP, so all
// blocks reading a given tau row live on ONE XCD -> each tau/inv line is
// fetched into exactly one L2 (tau HBM traffic ~8x down vs default
// round-robin dispatch spreading same-row blocks across all 8 XCDs).

typedef int   iv4 __attribute__((ext_vector_type(4)));
typedef float fv4 __attribute__((ext_vector_type(4)));

__global__ void fill_inv_kernel(int* __restrict__ inv, int n4) {
    int t = blockIdx.x * blockDim.x + threadIdx.x;
    int stride = gridDim.x * blockDim.x;
    iv4 m = (iv4)(-1);
    for (int i = t; i < n4; i += stride)
        ((iv4*)inv)[i] = m;
}

__global__ void build_inv_kernel(const int* __restrict__ idx,
                                 int* __restrict__ inv, int na) {
    int j = blockIdx.x * blockDim.x + threadIdx.x;
    if (j < na) inv[idx[j]] = j;   // indices unique -> no race
}

// 1D grid: nseg * NXCD blocks. bid&7 = row-group (== XCD under round-robin
// dispatch), bid>>3 = 1024-pixel segment. Each thread: 4 consecutive pixels,
// rows_per_blk rows.
__global__ __launch_bounds__(256)
void gather_rows_kernel(const float* __restrict__ tau,
                        const float* __restrict__ w,
                        const int* __restrict__ inv,
                        float* __restrict__ out,
                        int na, int p,
                        int rows_per_blk, int batch) {
    int bid = blockIdx.x;
    int rg  = bid & 7;          // row-group == XCD (round-robin assumption)
    int seg = bid >> 3;         // pixel segment
    int p4  = seg * blockDim.x + threadIdx.x;

    iv4 iv = ((const iv4*)inv)[p4];          // read once, lives in VGPRs
    float w0 = (iv.x >= 0) ? w[iv.x] : 0.0f; // row-invariant weights, hoisted
    float w1 = (iv.y >= 0) ? w[iv.y] : 0.0f;
    float w2 = (iv.z >= 0) ? w[iv.z] : 0.0f;
    float w3 = (iv.w >= 0) ? w[iv.w] : 0.0f;

    int b0 = rg * rows_per_blk;
    int bend = b0 + rows_per_blk;
    if (bend > batch) bend = batch;

    const float* taub = tau + (size_t)b0 * (size_t)na;
    fv4* dst = (fv4*)(out + (size_t)b0 * (size_t)p) + p4;
    int pq = p >> 2;

    #pragma unroll 4
    for (int b = b0; b < bend; ++b) {
        fv4 o;
        o.x = (iv.x >= 0) ? taub[iv.x] * w0 : 0.0f;
        o.y = (iv.y >= 0) ? taub[iv.y] * w1 : 0.0f;
        o.z = (iv.z >= 0) ? taub[iv.z] * w2 : 0.0f;
        o.w = (iv.w >= 0) ? taub[iv.w] * w3 : 0.0f;
        __builtin_nontemporal_store(o, dst);  // full-line coalesced NT stream
        taub += na;
        dst += pq;
    }
}

// ---------- fallback path (only if ws_size too small for inv map) ----------
__global__ void zero_out_kernel(float* __restrict__ out, long long n4) {
    long long t = (long long)blockIdx.x * blockDim.x + threadIdx.x;
    long long stride = (long long)gridDim.x * blockDim.x;
    fv4 z = (fv4)(0.0f);
    for (long long i = t; i < n4; i += stride)
        __builtin_nontemporal_store(z, (fv4*)out + i);
}

__global__ void scatter_kernel(const float* __restrict__ tau,
                               const float* __restrict__ w,
                               const int* __restrict__ idx,
                               float* __restrict__ out,
                               int na, int p, int batch) {
    int j = blockIdx.x * blockDim.x + threadIdx.x;
    if (j >= na) return;
    int pix = idx[j];
    float ww = w[j];
    for (int b = 0; b < batch; ++b)
        out[(size_t)b * p + pix] = tau[(size_t)b * na + j] * ww;
}

extern "C" void kernel_launch(void* const* d_in, const int* in_sizes, int n_in,
                              void* d_out, int out_size, void* d_ws, size_t ws_size,
                              hipStream_t stream) {
    const float* tau = (const float*)d_in[0];
    const float* w   = (const float*)d_in[1];
    const int*   idx = (const int*)d_in[2];
    float* out = (float*)d_out;

    int na = in_sizes[1];                        // 65536
    int batch = in_sizes[0] / na;                // 256
    int p = (int)((long long)out_size / batch);  // 1048576

    if (ws_size >= (size_t)p * sizeof(int) && (p % 1024) == 0 && batch >= 8) {
        int* inv = (int*)d_ws;
        int n4 = p / 4;
        fill_inv_kernel<<<dim3(1024), dim3(256), 0, stream>>>(inv, n4);
        build_inv_kernel<<<dim3((na + 255) / 256), dim3(256), 0, stream>>>(idx, inv, na);

        const int ROW_GROUPS = 8;                            // == NXCD
        int rows_per_blk = (batch + ROW_GROUPS - 1) / ROW_GROUPS;  // 32
        int nseg = p / 1024;                                 // 1024 segments
        gather_rows_kernel<<<dim3(nseg * ROW_GROUPS), dim3(256), 0, stream>>>(
            tau, w, inv, out, na, p, rows_per_blk, batch);
    } else {
        long long n4 = ((long long)out_size) / 4;
        zero_out_kernel<<<dim3(2048), dim3(256), 0, stream>>>(out, n4);
        scatter_kernel<<<dim3((na + 255) / 256), dim3(256), 0, stream>>>(
            tau, w, idx, out, na, p, batch);
    }
}